// Round 4
// baseline (533.190 us; speedup 1.0000x reference)
//
#include <hip/hip_runtime.h>

typedef __attribute__((ext_vector_type(8))) short short8;
typedef __attribute__((ext_vector_type(4))) float f32x4;

#define IN_F 256
#define OUT_F 128

__device__ __forceinline__ unsigned short f2bf(float f) {
    union { float f; unsigned int i; } v; v.f = f;
    unsigned int u = v.i;
    return (unsigned short)((u + 0x7fffu + ((u >> 16) & 1u)) >> 16);
}

// ---------------- degree histogram ----------------
__global__ __launch_bounds__(256) void k_deg(const int* __restrict__ col, int* __restrict__ deg, int E) {
    int e = blockIdx.x * 256 + threadIdx.x;
    if (e < E) atomicAdd(&deg[col[e]], 1);
}

// ---------------- dis = rsqrt(deg+1) ----------------
__global__ __launch_bounds__(256) void k_dis(const int* __restrict__ deg, float* __restrict__ dis, int n) {
    int i = blockIdx.x * 256 + threadIdx.x;
    if (i < n) dis[i] = rsqrtf((float)deg[i] + 1.0f);
}

// ---------------- 3-kernel exclusive scan over deg (chunk = 1024) ----------------
__global__ __launch_bounds__(256) void k_scan1(const int* __restrict__ deg, int* __restrict__ bsum, int n) {
    __shared__ int sd[256];
    int t = threadIdx.x;
    int base = blockIdx.x * 1024 + t * 4;
    int s = 0;
#pragma unroll
    for (int i = 0; i < 4; i++) if (base + i < n) s += deg[base + i];
    sd[t] = s; __syncthreads();
    for (int off = 128; off > 0; off >>= 1) {
        if (t < off) sd[t] += sd[t + off];
        __syncthreads();
    }
    if (t == 0) bsum[blockIdx.x] = sd[0];
}

// one-block exclusive scan over block sums (nb <= 256)
__global__ __launch_bounds__(256) void k_scan2(int* __restrict__ bsum, int nb) {
    __shared__ int sd[256];
    int t = threadIdx.x;
    int v = (t < nb) ? bsum[t] : 0;
    sd[t] = v; __syncthreads();
    for (int off = 1; off < 256; off <<= 1) {
        int add = (t >= off) ? sd[t - off] : 0;
        __syncthreads();
        sd[t] += add;
        __syncthreads();
    }
    if (t < nb) bsum[t] = sd[t] - v;   // exclusive
}

__global__ __launch_bounds__(256) void k_scan3(const int* __restrict__ deg, const int* __restrict__ bsum,
                                               int* __restrict__ offs, int* __restrict__ cursor, int n) {
    __shared__ int sd[256];
    int t = threadIdx.x;
    int base = blockIdx.x * 1024 + t * 4;
    int v[4]; int s = 0;
#pragma unroll
    for (int i = 0; i < 4; i++) { v[i] = (base + i < n) ? deg[base + i] : 0; s += v[i]; }
    sd[t] = s; __syncthreads();
    for (int off = 1; off < 256; off <<= 1) {
        int add = (t >= off) ? sd[t - off] : 0;
        __syncthreads();
        sd[t] += add;
        __syncthreads();
    }
    int acc = sd[t] - s + bsum[blockIdx.x];  // exclusive prefix across threads + block base
#pragma unroll
    for (int i = 0; i < 4; i++) {
        int idx = base + i;
        if (idx < n) { offs[idx] = acc; cursor[idx] = acc; acc += v[i]; }
    }
}

// ---------------- counting-sort scatter: CSR slot <- (src_row, dis[src]) ----------------
__global__ __launch_bounds__(256) void k_scatter(const int* __restrict__ row, const int* __restrict__ col,
                                                 const float* __restrict__ dis, int* __restrict__ cursor,
                                                 int2* __restrict__ src, int E) {
    int e = blockIdx.x * 256 + threadIdx.x;
    if (e < E) {
        int c = col[e];
        int r = row[e];
        int pos = atomicAdd(&cursor[c], 1);
        int2 pk; pk.x = r; pk.y = __float_as_int(dis[r]);
        src[pos] = pk;
    }
}

// ---------------- transpose+convert W[256][128] f32 -> Wt[128][256] bf16 ----------------
__global__ __launch_bounds__(256) void k_transposeW(const float* __restrict__ W,
                                                    unsigned short* __restrict__ Wt) {
    int idx = blockIdx.x * 256 + threadIdx.x;
    if (idx < IN_F * OUT_F) {
        int k = idx >> 7;       // 0..255
        int n = idx & 127;      // 0..127
        Wt[n * IN_F + k] = f2bf(W[idx]);
    }
}

// ---------------- GEMM: h[N][128] = bf16(x[N][256] f32) @ W + b ; h fp32 ----------------
__global__ __launch_bounds__(256) void k_gemm(const float* __restrict__ x,
                                              const unsigned short* __restrict__ Wt,
                                              const float* __restrict__ bias,
                                              float* __restrict__ h, int nrows) {
    int wave = threadIdx.x >> 6;       // 0..3
    int lane = threadIdx.x & 63;
    int m = lane & 15;
    int quad = lane >> 4;

    int row = blockIdx.x * 64 + wave * 16 + m;
    int rclamp = row < nrows ? row : (nrows - 1);
    const float* xrow = x + (size_t)rclamp * IN_F;

    f32x4 acc[8];
#pragma unroll
    for (int ct = 0; ct < 8; ct++) acc[ct] = (f32x4){0.f, 0.f, 0.f, 0.f};

#pragma unroll
    for (int k0 = 0; k0 < IN_F; k0 += 32) {
        const float4* ap = (const float4*)(xrow + k0 + quad * 8);
        float4 a0 = ap[0];
        float4 a1 = ap[1];
        short8 a;
        a[0] = (short)f2bf(a0.x); a[1] = (short)f2bf(a0.y);
        a[2] = (short)f2bf(a0.z); a[3] = (short)f2bf(a0.w);
        a[4] = (short)f2bf(a1.x); a[5] = (short)f2bf(a1.y);
        a[6] = (short)f2bf(a1.z); a[7] = (short)f2bf(a1.w);
#pragma unroll
        for (int ct = 0; ct < 8; ct++) {
            int n = ct * 16 + m;   // B fragment: n = lane&15
            short8 bf = *(const short8*)(Wt + (size_t)n * IN_F + k0 + quad * 8);
            acc[ct] = __builtin_amdgcn_mfma_f32_16x16x32_bf16(a, bf, acc[ct], 0, 0, 0);
        }
    }

    // C/D: col = lane&15, row = quad*4 + reg
    int orow_base = blockIdx.x * 64 + wave * 16 + quad * 4;
    int ocol = lane & 15;
#pragma unroll
    for (int ct = 0; ct < 8; ct++) {
        float bv = bias[ct * 16 + ocol];
#pragma unroll
        for (int r = 0; r < 4; r++) {
            int orow = orow_base + r;
            if (orow < nrows)
                h[(size_t)orow * OUT_F + ct * 16 + ocol] = acc[ct][r] + bv;
        }
    }
}

// ---------------- aggregation: one wave per node, register accumulation, fp32 out ----------------
__global__ __launch_bounds__(256) void k_agg(const float* __restrict__ h,
                                             const float* __restrict__ dis,
                                             const int* __restrict__ offs, const int* __restrict__ deg,
                                             const int2* __restrict__ src,
                                             float* __restrict__ out, int n) {
    int node = blockIdx.x * 4 + (threadIdx.x >> 6);
    if (node >= n) return;
    int lane = threadIdx.x & 63;

    float di = dis[node];
    const float2* hn = (const float2*)(h + (size_t)node * OUT_F);
    float2 v = hn[lane];
    float ax = v.x * di;   // self-loop (pre final *di)
    float ay = v.y * di;

    int start = offs[node];
    int cnt = deg[node];
    for (int j = 0; j < cnt; j++) {
        int2 e = src[start + j];
        float dr = __int_as_float(e.y);
        const float2* hr = (const float2*)(h + (size_t)e.x * OUT_F);
        float2 w = hr[lane];
        ax += w.x * dr;
        ay += w.y * dr;
    }
    ax *= di; ay *= di;

    float2 o;
    o.x = fmaxf(ax, 0.f);
    o.y = fmaxf(ay, 0.f);
    *(float2*)(out + (size_t)node * OUT_F + lane * 2) = o;
}

static inline size_t alignup(size_t v, size_t a) { return (v + a - 1) & ~(a - 1); }

extern "C" void kernel_launch(void* const* d_in, const int* in_sizes, int n_in,
                              void* d_out, int out_size, void* d_ws, size_t ws_size,
                              hipStream_t stream) {
    const float* x  = (const float*)d_in[0];
    const int* ei   = (const int*)d_in[1];
    const float* W  = (const float*)d_in[2];
    const float* b  = (const float*)d_in[3];
    float* out      = (float*)d_out;

    const int N = in_sizes[0] / IN_F;      // 100000
    const int E = in_sizes[1] / 2;         // 1600000
    const int* rowp = ei;
    const int* colp = ei + E;

    // workspace carve (~66 MB total)
    char* ws = (char*)d_ws;
    size_t off = 0;
    int*   deg    = (int*)(ws + off);   off = alignup(off + (size_t)N * 4, 256);
    float* dis    = (float*)(ws + off); off = alignup(off + (size_t)N * 4, 256);
    int*   offs   = (int*)(ws + off);   off = alignup(off + (size_t)N * 4, 256);
    int*   cursor = (int*)(ws + off);   off = alignup(off + (size_t)N * 4, 256);
    int*   bsum   = (int*)(ws + off);   off = alignup(off + 4096, 256);
    unsigned short* Wt = (unsigned short*)(ws + off); off = alignup(off + (size_t)IN_F * OUT_F * 2, 256);
    int2*  src    = (int2*)(ws + off);  off = alignup(off + (size_t)E * 8, 256);
    float* h      = (float*)(ws + off); off = alignup(off + (size_t)N * OUT_F * 4, 256);

    (void)hipMemsetAsync(deg, 0, (size_t)N * 4, stream);

    k_deg<<<(E + 255) / 256, 256, 0, stream>>>(colp, deg, E);
    k_dis<<<(N + 255) / 256, 256, 0, stream>>>(deg, dis, N);

    int nb = (N + 1023) / 1024;            // 98 <= 256
    k_scan1<<<nb, 256, 0, stream>>>(deg, bsum, N);
    k_scan2<<<1, 256, 0, stream>>>(bsum, nb);
    k_scan3<<<nb, 256, 0, stream>>>(deg, bsum, offs, cursor, N);

    k_scatter<<<(E + 255) / 256, 256, 0, stream>>>(rowp, colp, dis, cursor, src, E);

    k_transposeW<<<(IN_F * OUT_F + 255) / 256, 256, 0, stream>>>(W, Wt);
    k_gemm<<<(N + 63) / 64, 256, 0, stream>>>(x, Wt, b, h, N);

    k_agg<<<(N + 3) / 4, 256, 0, stream>>>(h, dis, offs, deg, src, out, N);
}

// Round 5
// 428.696 us; speedup vs baseline: 1.2437x; 1.2437x over previous
//
#include <hip/hip_runtime.h>

typedef __attribute__((ext_vector_type(8))) short short8;
typedef __attribute__((ext_vector_type(4))) float f32x4;

#define IN_F 256
#define OUT_F 128

__device__ __forceinline__ float bf2f(unsigned int u16) {
    union { unsigned int i; float f; } v; v.i = u16 << 16; return v.f;
}
__device__ __forceinline__ unsigned short f2bf(float f) {
    union { float f; unsigned int i; } v; v.f = f;
    unsigned int u = v.i;
    return (unsigned short)((u + 0x7fffu + ((u >> 16) & 1u)) >> 16);
}

// ---------------- degree histogram ----------------
__global__ __launch_bounds__(256) void k_deg(const int* __restrict__ col, int* __restrict__ deg, int E) {
    int e = blockIdx.x * 256 + threadIdx.x;
    if (e < E) atomicAdd(&deg[col[e]], 1);
}

// ---------------- 3-kernel exclusive scan over deg (chunk = 1024) ----------------
__global__ __launch_bounds__(256) void k_scan1(const int* __restrict__ deg, int* __restrict__ bsum, int n) {
    __shared__ int sd[256];
    int t = threadIdx.x;
    int base = blockIdx.x * 1024 + t * 4;
    int s = 0;
#pragma unroll
    for (int i = 0; i < 4; i++) if (base + i < n) s += deg[base + i];
    sd[t] = s; __syncthreads();
    for (int off = 128; off > 0; off >>= 1) {
        if (t < off) sd[t] += sd[t + off];
        __syncthreads();
    }
    if (t == 0) bsum[blockIdx.x] = sd[0];
}

// one-block exclusive scan over block sums (nb <= 256)
__global__ __launch_bounds__(256) void k_scan2(int* __restrict__ bsum, int nb) {
    __shared__ int sd[256];
    int t = threadIdx.x;
    int v = (t < nb) ? bsum[t] : 0;
    sd[t] = v; __syncthreads();
    for (int off = 1; off < 256; off <<= 1) {
        int add = (t >= off) ? sd[t - off] : 0;
        __syncthreads();
        sd[t] += add;
        __syncthreads();
    }
    if (t < nb) bsum[t] = sd[t] - v;   // exclusive
}

// scan3 also emits dis = rsqrt(deg+1)
__global__ __launch_bounds__(256) void k_scan3(const int* __restrict__ deg, const int* __restrict__ bsum,
                                               int* __restrict__ offs, int* __restrict__ cursor,
                                               float* __restrict__ dis, int n) {
    __shared__ int sd[256];
    int t = threadIdx.x;
    int base = blockIdx.x * 1024 + t * 4;
    int v[4]; int s = 0;
#pragma unroll
    for (int i = 0; i < 4; i++) { v[i] = (base + i < n) ? deg[base + i] : 0; s += v[i]; }
    sd[t] = s; __syncthreads();
    for (int off = 1; off < 256; off <<= 1) {
        int add = (t >= off) ? sd[t - off] : 0;
        __syncthreads();
        sd[t] += add;
        __syncthreads();
    }
    int acc = sd[t] - s + bsum[blockIdx.x];  // exclusive prefix across threads + block base
#pragma unroll
    for (int i = 0; i < 4; i++) {
        int idx = base + i;
        if (idx < n) {
            offs[idx] = acc; cursor[idx] = acc; acc += v[i];
            dis[idx] = rsqrtf((float)v[i] + 1.0f);
        }
    }
}

// ---------------- counting-sort scatter: CSR slot <- (src_row, dis[src]) ----------------
__global__ __launch_bounds__(256) void k_scatter(const int* __restrict__ row, const int* __restrict__ col,
                                                 const float* __restrict__ dis, int* __restrict__ cursor,
                                                 int2* __restrict__ src, int E) {
    int e = blockIdx.x * 256 + threadIdx.x;
    if (e < E) {
        int c = col[e];
        int r = row[e];
        int pos = atomicAdd(&cursor[c], 1);
        int2 pk; pk.x = r; pk.y = __float_as_int(dis[r]);
        src[pos] = pk;
    }
}

// ---------------- transpose+convert W[256][128] f32 -> Wt[128][256] bf16 ----------------
__global__ __launch_bounds__(256) void k_transposeW(const float* __restrict__ W,
                                                    unsigned short* __restrict__ Wt) {
    int idx = blockIdx.x * 256 + threadIdx.x;
    if (idx < IN_F * OUT_F) {
        int k = idx >> 7;       // 0..255
        int n = idx & 127;      // 0..127
        Wt[n * IN_F + k] = f2bf(W[idx]);
    }
}

// ---------------- GEMM: hb[N][128] = bf16( bf16(x) @ W + b ) ----------------
__global__ __launch_bounds__(256) void k_gemm(const float* __restrict__ x,
                                              const unsigned short* __restrict__ Wt,
                                              const float* __restrict__ bias,
                                              unsigned short* __restrict__ hb, int nrows) {
    int wave = threadIdx.x >> 6;       // 0..3
    int lane = threadIdx.x & 63;
    int m = lane & 15;
    int quad = lane >> 4;

    int row = blockIdx.x * 64 + wave * 16 + m;
    int rclamp = row < nrows ? row : (nrows - 1);
    const float* xrow = x + (size_t)rclamp * IN_F;

    f32x4 acc[8];
#pragma unroll
    for (int ct = 0; ct < 8; ct++) acc[ct] = (f32x4){0.f, 0.f, 0.f, 0.f};

#pragma unroll
    for (int k0 = 0; k0 < IN_F; k0 += 32) {
        const float4* ap = (const float4*)(xrow + k0 + quad * 8);
        float4 a0 = ap[0];
        float4 a1 = ap[1];
        short8 a;
        a[0] = (short)f2bf(a0.x); a[1] = (short)f2bf(a0.y);
        a[2] = (short)f2bf(a0.z); a[3] = (short)f2bf(a0.w);
        a[4] = (short)f2bf(a1.x); a[5] = (short)f2bf(a1.y);
        a[6] = (short)f2bf(a1.z); a[7] = (short)f2bf(a1.w);
#pragma unroll
        for (int ct = 0; ct < 8; ct++) {
            int n = ct * 16 + m;   // B fragment: n = lane&15
            short8 bf = *(const short8*)(Wt + (size_t)n * IN_F + k0 + quad * 8);
            acc[ct] = __builtin_amdgcn_mfma_f32_16x16x32_bf16(a, bf, acc[ct], 0, 0, 0);
        }
    }

    // C/D: col = lane&15, row = quad*4 + reg
    int orow_base = blockIdx.x * 64 + wave * 16 + quad * 4;
    int ocol = lane & 15;
#pragma unroll
    for (int ct = 0; ct < 8; ct++) {
        float bv = bias[ct * 16 + ocol];
#pragma unroll
        for (int r = 0; r < 4; r++) {
            int orow = orow_base + r;
            if (orow < nrows)
                hb[(size_t)orow * OUT_F + ct * 16 + ocol] = f2bf(acc[ct][r] + bv);
        }
    }
}

// ---------------- aggregation: wave/node, lane-coop src load + unroll-8 gathers ----------------
__global__ __launch_bounds__(256) void k_agg(const unsigned short* __restrict__ hb,
                                             const float* __restrict__ dis,
                                             const int* __restrict__ offs, const int* __restrict__ deg,
                                             const int2* __restrict__ src,
                                             float* __restrict__ out, int n) {
    int node = blockIdx.x * 4 + (threadIdx.x >> 6);
    if (node >= n) return;
    int lane = threadIdx.x & 63;

    float di = dis[node];
    unsigned int v = *(const unsigned int*)(hb + (size_t)node * OUT_F + lane * 2);
    float ax = bf2f(v & 0xffffu) * di;   // self-loop (pre final *di)
    float ay = bf2f(v >> 16) * di;

    int start = offs[node];
    int cnt = deg[node];

    for (int base = 0; base < cnt; base += 64) {
        int m = cnt - base; if (m > 64) m = 64;
        int2 e;
        if (lane < m) {
            e = src[start + base + lane];    // coalesced, up to 64 edges in one shot
        } else {
            e.x = node; e.y = 0;              // zero weight -> contributes nothing
        }
        int mround = (m + 7) & ~7;
        for (int j = 0; j < mround; j += 8) {
            int rr[8]; float dd[8];
#pragma unroll
            for (int k = 0; k < 8; k++) {
                rr[k] = __shfl(e.x, j + k);
                dd[k] = __int_as_float(__shfl(e.y, j + k));
            }
            unsigned int w[8];
#pragma unroll
            for (int k = 0; k < 8; k++)
                w[k] = *(const unsigned int*)(hb + (size_t)rr[k] * OUT_F + lane * 2);
#pragma unroll
            for (int k = 0; k < 8; k++) {
                ax += bf2f(w[k] & 0xffffu) * dd[k];
                ay += bf2f(w[k] >> 16) * dd[k];
            }
        }
    }

    ax *= di; ay *= di;
    float2 o;
    o.x = fmaxf(ax, 0.f);
    o.y = fmaxf(ay, 0.f);
    *(float2*)(out + (size_t)node * OUT_F + lane * 2) = o;
}

static inline size_t alignup(size_t v, size_t a) { return (v + a - 1) & ~(a - 1); }

extern "C" void kernel_launch(void* const* d_in, const int* in_sizes, int n_in,
                              void* d_out, int out_size, void* d_ws, size_t ws_size,
                              hipStream_t stream) {
    const float* x  = (const float*)d_in[0];
    const int* ei   = (const int*)d_in[1];
    const float* W  = (const float*)d_in[2];
    const float* b  = (const float*)d_in[3];
    float* out      = (float*)d_out;

    const int N = in_sizes[0] / IN_F;      // 100000
    const int E = in_sizes[1] / 2;         // 1600000
    const int* rowp = ei;
    const int* colp = ei + E;

    // workspace carve (~40 MB total)
    char* ws = (char*)d_ws;
    size_t off = 0;
    int*   deg    = (int*)(ws + off);   off = alignup(off + (size_t)N * 4, 256);
    float* dis    = (float*)(ws + off); off = alignup(off + (size_t)N * 4, 256);
    int*   offs   = (int*)(ws + off);   off = alignup(off + (size_t)N * 4, 256);
    int*   cursor = (int*)(ws + off);   off = alignup(off + (size_t)N * 4, 256);
    int*   bsum   = (int*)(ws + off);   off = alignup(off + 4096, 256);
    unsigned short* Wt = (unsigned short*)(ws + off); off = alignup(off + (size_t)IN_F * OUT_F * 2, 256);
    int2*  src    = (int2*)(ws + off);  off = alignup(off + (size_t)E * 8, 256);
    unsigned short* hb = (unsigned short*)(ws + off); off = alignup(off + (size_t)N * OUT_F * 2, 256);

    (void)hipMemsetAsync(deg, 0, (size_t)N * 4, stream);

    k_deg<<<(E + 255) / 256, 256, 0, stream>>>(colp, deg, E);

    int nb = (N + 1023) / 1024;            // 98 <= 256
    k_scan1<<<nb, 256, 0, stream>>>(deg, bsum, N);
    k_scan2<<<1, 256, 0, stream>>>(bsum, nb);
    k_scan3<<<nb, 256, 0, stream>>>(deg, bsum, offs, cursor, dis, N);

    k_scatter<<<(E + 255) / 256, 256, 0, stream>>>(rowp, colp, dis, cursor, src, E);

    k_transposeW<<<(IN_F * OUT_F + 255) / 256, 256, 0, stream>>>(W, Wt);
    k_gemm<<<(N + 63) / 64, 256, 0, stream>>>(x, Wt, b, hb, N);

    k_agg<<<(N + 3) / 4, 256, 0, stream>>>(hb, dis, offs, deg, src, out, N);
}